// Round 9
// baseline (797.392 us; speedup 1.0000x reference)
//
#include <hip/hip_runtime.h>

#define N_NODES 50000
#define N_EDGES 800000
#define IN_CH   64
#define OUT_CH  128
#define FEAT    192                          // IN_CH * 3 powers
#define NB      ((N_NODES + 63) / 64)        // 782 dst-buckets of 64 nodes
#define EPB     1024                         // edges per partition block
#define NPB     ((N_EDGES + EPB - 1) / EPB)  // 782 edge-blocks
#define JPT     ((NPB + 255) / 256)          // 4 edge-blocks per scan thread
#define N_TILES (N_NODES / 16)               // 3125 wave-tiles for GEMM
#define CAST_BLOCKS  ((N_NODES * IN_CH / 8 + 255) / 256)  // 1563
#define WFRAG_BLOCKS ((FEAT * OUT_CH + 255) / 256)        // 96

typedef __attribute__((ext_vector_type(8))) short short8;  // 8 bf16 (4 VGPRs)
typedef __attribute__((ext_vector_type(4))) float f32x4;

static __device__ __forceinline__ unsigned short f2bf(float f) {
  unsigned int u = __float_as_uint(f);
  u += 0x7FFFu + ((u >> 16) & 1u);
  return (unsigned short)(u >> 16);
}
static __device__ __forceinline__ float bf2f(unsigned int s) {
  return __uint_as_float(s << 16);
}

// ---------------------------------------------------------------------------
// P1: per-edge-block histogram over the 782 dst buckets (dst>>6).
// LDS atomics only; coalesced row write hist[b][k].
// ---------------------------------------------------------------------------
__global__ __launch_bounds__(256) void part_hist_kernel(
    const int* __restrict__ ei, int* __restrict__ hist) {
  __shared__ int lh[NB];
  const int b = blockIdx.x;
  for (int i = threadIdx.x; i < NB; i += 256) lh[i] = 0;
  __syncthreads();
  const int e0 = b * EPB;
  const int e1 = (e0 + EPB < N_EDGES) ? e0 + EPB : N_EDGES;
  for (int e = e0 + threadIdx.x; e < e1; e += 256)
    atomicAdd(&lh[((unsigned)ei[N_EDGES + e]) >> 6], 1);
  __syncthreads();
  for (int i = threadIdx.x; i < NB; i += 256) hist[b * NB + i] = lh[i];
}

// ---------------------------------------------------------------------------
// P2a: per-bucket exclusive scan across the 782 edge-blocks.
// Block k: offs_t[k][j] = sum_{j'<j} hist[j'][k]; total[k] = full sum.
// ---------------------------------------------------------------------------
__global__ __launch_bounds__(256) void part_scan_kernel(
    const int* __restrict__ hist, int* __restrict__ offs_t,
    int* __restrict__ total) {
  __shared__ int part[256];
  const int k = blockIdx.x;
  const int t = threadIdx.x;
  int loc[JPT];
  int sum = 0;
#pragma unroll
  for (int u = 0; u < JPT; ++u) {
    const int j = t * JPT + u;
    const int v = (j < NPB) ? hist[j * NB + k] : 0;
    loc[u] = v;
    sum += v;
  }
  part[t] = sum;
  __syncthreads();
  for (int off = 1; off < 256; off <<= 1) {
    const int v = (t >= off) ? part[t - off] : 0;
    __syncthreads();
    part[t] += v;
    __syncthreads();
  }
  int run = part[t] - sum;
#pragma unroll
  for (int u = 0; u < JPT; ++u) {
    const int j = t * JPT + u;
    if (j < NPB) offs_t[k * NPB + j] = run;
    run += loc[u];
  }
  if (t == 255) total[k] = part[255];
}

// ---------------------------------------------------------------------------
// P2b: exclusive scan of the 782 bucket totals -> boffset[0..NB].
// ---------------------------------------------------------------------------
__global__ __launch_bounds__(1024) void part_scan2_kernel(
    const int* __restrict__ total, int* __restrict__ boffset) {
  __shared__ int s[1024];
  const int tid = threadIdx.x;
  const int v = (tid < NB) ? total[tid] : 0;
  s[tid] = v;
  __syncthreads();
  for (int off = 1; off < 1024; off <<= 1) {
    const int t = (tid >= off) ? s[tid - off] : 0;
    __syncthreads();
    s[tid] += t;
    __syncthreads();
  }
  if (tid < NB) boffset[tid] = s[tid] - v;
  if (tid == 0) boffset[NB] = N_EDGES;
}

// ---------------------------------------------------------------------------
// P3: deterministic fill. Each edge-block writes its edges to precomputed
// per-bucket bases; only LDS atomics for intra-block rank.
// Packed word: (src<<6)|(dst&63)  (src < 2^16, fits easily).
// ---------------------------------------------------------------------------
__global__ __launch_bounds__(256) void part_fill_kernel(
    const int* __restrict__ ei, const int* __restrict__ boffset,
    const int* __restrict__ offs_t, unsigned* __restrict__ pairs) {
  __shared__ int cur[NB];
  const int b = blockIdx.x;
  for (int k = threadIdx.x; k < NB; k += 256)
    cur[k] = boffset[k] + offs_t[k * NPB + b];
  __syncthreads();
  const int e0 = b * EPB;
  const int e1 = (e0 + EPB < N_EDGES) ? e0 + EPB : N_EDGES;
  for (int e = e0 + threadIdx.x; e < e1; e += 256) {
    const unsigned s = (unsigned)ei[e];
    const unsigned d = (unsigned)ei[N_EDGES + e];
    const int pos = atomicAdd(&cur[d >> 6], 1);
    pairs[pos] = (s << 6) | (d & 63u);
  }
}

// ---------------------------------------------------------------------------
// Propagation hop, fused with per-node grouping: one block per 64-node
// bucket. Accumulate incoming rows into a padded LDS f32 tile ([64][65] —
// pad breaks the 32-way bank conflict on reads), then emit bf16 rows.
// 8 lanes per edge (s = channel slice), 32 edges in flight per block.
// ---------------------------------------------------------------------------
__global__ __launch_bounds__(256) void scatter_lds_kernel(
    const unsigned short* __restrict__ hin, const int* __restrict__ boffset,
    const unsigned* __restrict__ pairs, unsigned short* __restrict__ hout) {
  __shared__ float hacc[64 * 65];
  const int tid = threadIdx.x;
  const int k = blockIdx.x;

  for (int i = tid; i < 64 * 65; i += 256) hacc[i] = 0.0f;
  __syncthreads();

  const int base = boffset[k];
  const int limit = boffset[k + 1];
  const int g = tid >> 3;  // edge slot 0..31
  const int s = tid & 7;   // channel slice 0..7

  for (int i = base + g; i < limit; i += 32) {
    const unsigned p = pairs[i];
    const int src = (int)(p >> 6);
    const int local = (int)(p & 63u);
    const uint4 v = *reinterpret_cast<const uint4*>(
        hin + (size_t)src * IN_CH + s * 8);
    float* row = &hacc[local * 65 + s * 8];
    atomicAdd(row + 0, bf2f(v.x & 0xffffu));
    atomicAdd(row + 1, bf2f(v.x >> 16));
    atomicAdd(row + 2, bf2f(v.y & 0xffffu));
    atomicAdd(row + 3, bf2f(v.y >> 16));
    atomicAdd(row + 4, bf2f(v.z & 0xffffu));
    atomicAdd(row + 5, bf2f(v.z >> 16));
    atomicAdd(row + 6, bf2f(v.w & 0xffffu));
    atomicAdd(row + 7, bf2f(v.w >> 16));
  }
  __syncthreads();

  // Emit: 4 threads per node, 16 channels each (2x 16B stores).
  const int node_l = tid >> 2;       // 0..63
  const int c0 = (tid & 3) * 16;     // 0,16,32,48
  const int node = k * 64 + node_l;
  if (node < N_NODES) {
    const float* row = &hacc[node_l * 65 + c0];
    union { unsigned u[4]; uint4 v; } o0, o1;
#pragma unroll
    for (int q = 0; q < 4; ++q) {
      o0.u[q] = (unsigned)f2bf(row[q * 2]) |
                ((unsigned)f2bf(row[q * 2 + 1]) << 16);
      o1.u[q] = (unsigned)f2bf(row[8 + q * 2]) |
                ((unsigned)f2bf(row[8 + q * 2 + 1]) << 16);
    }
    uint4* dst = reinterpret_cast<uint4*>(hout + (size_t)node * IN_CH + c0);
    dst[0] = o0.v;
    dst[1] = o1.v;
  }
}

// ---------------------------------------------------------------------------
// Fused preprocessing: blocks [0, CAST_BLOCKS) cast x f32->bf16 (8/thread);
// blocks [CAST_BLOCKS, +WFRAG_BLOCKS) shuffle W into MFMA fragment order:
// Wf[((kk*8+nt)*64 + lane)*8 + j] = W[nt*16+(lane&15)][kk*32+(lane>>4)*8+j]
// ---------------------------------------------------------------------------
__global__ __launch_bounds__(256) void prep_kernel(
    const float* __restrict__ x, const float* __restrict__ W,
    unsigned short* __restrict__ xb, unsigned short* __restrict__ Wf) {
  if (blockIdx.x < CAST_BLOCKS) {
    const int t = blockIdx.x * 256 + threadIdx.x;
    if (t >= (N_NODES * IN_CH) / 8) return;
    const float4 a = reinterpret_cast<const float4*>(x)[t * 2];
    const float4 c = reinterpret_cast<const float4*>(x)[t * 2 + 1];
    union { unsigned int u[4]; uint4 v; } o;
    o.u[0] = (unsigned)f2bf(a.x) | ((unsigned)f2bf(a.y) << 16);
    o.u[1] = (unsigned)f2bf(a.z) | ((unsigned)f2bf(a.w) << 16);
    o.u[2] = (unsigned)f2bf(c.x) | ((unsigned)f2bf(c.y) << 16);
    o.u[3] = (unsigned)f2bf(c.z) | ((unsigned)f2bf(c.w) << 16);
    reinterpret_cast<uint4*>(xb)[t] = o.v;
  } else {
    const int t = (blockIdx.x - CAST_BLOCKS) * 256 + threadIdx.x;
    if (t >= FEAT * OUT_CH) return;
    const int j = t & 7;
    const int l = (t >> 3) & 63;
    const int nt = (t >> 9) & 7;
    const int kk = t >> 12;
    const int o = nt * 16 + (l & 15);
    const int k = kk * 32 + (l >> 4) * 8 + j;
    Wf[t] = f2bf(W[o * FEAT + k]);
  }
}

// ---------------------------------------------------------------------------
// MFMA GEMM: out[n,o] = b[o] + [xb|h1b|h2b][n,:] @ W[o,:]  (bf16 in, f32 acc)
// One wave per 16-node tile; 8 n-tiles of 16 out-ch; K = 6 chunks of 32.
// C/D (m89-verified): D[(l>>4)*4+r][l&15].
// ---------------------------------------------------------------------------
__global__ __launch_bounds__(256) void gemm_kernel(
    const unsigned short* __restrict__ xb,
    const unsigned short* __restrict__ h1b,
    const unsigned short* __restrict__ h2b,
    const unsigned short* __restrict__ Wf, const float* __restrict__ b,
    float* __restrict__ out) {
  const int wave = (blockIdx.x * 256 + threadIdx.x) >> 6;
  if (wave >= N_TILES) return;
  const int lane = threadIdx.x & 63;
  const int node0 = wave * 16;
  const int mrow = lane & 15;
  const int kg = lane >> 4;

  f32x4 acc[8];
#pragma unroll
  for (int nt = 0; nt < 8; ++nt) acc[nt] = (f32x4){0.f, 0.f, 0.f, 0.f};

  const unsigned short* const srcarr[3] = {xb, h1b, h2b};
#pragma unroll
  for (int kk = 0; kk < 6; ++kk) {
    const unsigned short* a = srcarr[kk >> 1];
    const short8 af = *reinterpret_cast<const short8*>(
        a + (size_t)(node0 + mrow) * IN_CH + (kk & 1) * 32 + kg * 8);
#pragma unroll
    for (int nt = 0; nt < 8; ++nt) {
      const short8 bf = *reinterpret_cast<const short8*>(
          Wf + ((size_t)(kk * 8 + nt) * 64 + lane) * 8);
      acc[nt] = __builtin_amdgcn_mfma_f32_16x16x32_bf16(af, bf, acc[nt], 0, 0, 0);
    }
  }

#pragma unroll
  for (int nt = 0; nt < 8; ++nt) {
    const int oc = nt * 16 + mrow;
    const float bias = b[oc];
#pragma unroll
    for (int r = 0; r < 4; ++r) {
      out[(size_t)(node0 + kg * 4 + r) * OUT_CH + oc] = acc[nt][r] + bias;
    }
  }
}

extern "C" void kernel_launch(void* const* d_in, const int* in_sizes, int n_in,
                              void* d_out, int out_size, void* d_ws,
                              size_t ws_size, hipStream_t stream) {
  const float* x = (const float*)d_in[0];
  const int* ei = (const int*)d_in[1];   // [2, N_EDGES], int32 per harness
  const float* W = (const float*)d_in[2];
  const float* b = (const float*)d_in[3];
  float* out = (float*)d_out;

  // Workspace layout (no aliasing; ~28 MB of the 256 MiB ws).
  char* p = (char*)d_ws;
  auto take = [&](size_t bytes) {
    char* r = p;
    p += (bytes + 255) & ~(size_t)255;
    return r;
  };
  unsigned short* xb  = (unsigned short*)take((size_t)N_NODES * IN_CH * 2);
  unsigned short* h1b = (unsigned short*)take((size_t)N_NODES * IN_CH * 2);
  unsigned short* h2b = (unsigned short*)take((size_t)N_NODES * IN_CH * 2);
  unsigned short* Wf  = (unsigned short*)take((size_t)FEAT * OUT_CH * 2);
  int* total   = (int*)take((size_t)NB * 4);
  int* boffset = (int*)take((size_t)(NB + 1) * 4);
  unsigned* pairs = (unsigned*)take((size_t)N_EDGES * 4);
  int* hist   = (int*)take((size_t)NPB * NB * 4);
  int* offs_t = (int*)take((size_t)NB * NPB * 4);

  // Deterministic two-level partition (no global atomics, no memset).
  part_hist_kernel<<<NPB, 256, 0, stream>>>(ei, hist);
  part_scan_kernel<<<NB, 256, 0, stream>>>(hist, offs_t, total);
  part_scan2_kernel<<<1, 1024, 0, stream>>>(total, boffset);
  part_fill_kernel<<<NPB, 256, 0, stream>>>(ei, boffset, offs_t, pairs);

  // Preprocessing (cast x, shuffle W) — independent of partition.
  prep_kernel<<<CAST_BLOCKS + WFRAG_BLOCKS, 256, 0, stream>>>(x, W, xb, Wf);

  // Hop 1: h1 = A*x; Hop 2: h2 = A*h1. Fused grouping+accumulate in LDS.
  scatter_lds_kernel<<<NB, 256, 0, stream>>>(xb, boffset, pairs, h1b);
  scatter_lds_kernel<<<NB, 256, 0, stream>>>(h1b, boffset, pairs, h2b);

  // out = [xb|h1b|h2b] @ W.T + b via MFMA.
  const int gemmblocks = (N_TILES + 3) / 4;  // 4 waves per block
  gemm_kernel<<<gemmblocks, 256, 0, stream>>>(xb, h1b, h2b, Wf, b, out);
}

// Round 10
// 167.976 us; speedup vs baseline: 4.7471x; 4.7471x over previous
//
#include <hip/hip_runtime.h>

#define N_NODES 50000
#define N_EDGES 800000
#define IN_CH   64
#define OUT_CH  128
#define FEAT    192                          // IN_CH * 3 powers
#define NB      ((N_NODES + 63) / 64)        // 782 dst-buckets of 64 nodes
#define EPB     1024                         // edges per partition block
#define NPB     ((N_EDGES + EPB - 1) / EPB)  // 782 edge-blocks
#define JPT     ((NPB + 255) / 256)          // 4 edge-blocks per scan thread
#define N_TILES (N_NODES / 16)               // 3125 wave-tiles for GEMM
#define CAST_BLOCKS  ((N_NODES * IN_CH / 8 + 255) / 256)  // 1563
#define WFRAG_BLOCKS ((FEAT * OUT_CH + 255) / 256)        // 96

typedef __attribute__((ext_vector_type(8))) short short8;  // 8 bf16 (4 VGPRs)
typedef __attribute__((ext_vector_type(4))) float f32x4;

static __device__ __forceinline__ unsigned short f2bf(float f) {
  unsigned int u = __float_as_uint(f);
  u += 0x7FFFu + ((u >> 16) & 1u);
  return (unsigned short)(u >> 16);
}
static __device__ __forceinline__ float bf2f(unsigned int s) {
  return __uint_as_float(s << 16);
}

// ---------------------------------------------------------------------------
// P1: per-edge-block histogram over the 782 dst buckets (dst>>6).
// LDS atomics only; coalesced row write hist[b][k].
// ---------------------------------------------------------------------------
__global__ __launch_bounds__(256) void part_hist_kernel(
    const int* __restrict__ ei, int* __restrict__ hist) {
  __shared__ int lh[NB];
  const int b = blockIdx.x;
  for (int i = threadIdx.x; i < NB; i += 256) lh[i] = 0;
  __syncthreads();
  const int e0 = b * EPB;
  const int e1 = (e0 + EPB < N_EDGES) ? e0 + EPB : N_EDGES;
  for (int e = e0 + threadIdx.x; e < e1; e += 256)
    atomicAdd(&lh[((unsigned)ei[N_EDGES + e]) >> 6], 1);
  __syncthreads();
  for (int i = threadIdx.x; i < NB; i += 256) hist[b * NB + i] = lh[i];
}

// ---------------------------------------------------------------------------
// P2a: per-bucket exclusive scan across the 782 edge-blocks.
// Block k: offs_t[k][j] = sum_{j'<j} hist[j'][k]; total[k] = full sum.
// ---------------------------------------------------------------------------
__global__ __launch_bounds__(256) void part_scan_kernel(
    const int* __restrict__ hist, int* __restrict__ offs_t,
    int* __restrict__ total) {
  __shared__ int part[256];
  const int k = blockIdx.x;
  const int t = threadIdx.x;
  int loc[JPT];
  int sum = 0;
#pragma unroll
  for (int u = 0; u < JPT; ++u) {
    const int j = t * JPT + u;
    const int v = (j < NPB) ? hist[j * NB + k] : 0;
    loc[u] = v;
    sum += v;
  }
  part[t] = sum;
  __syncthreads();
  for (int off = 1; off < 256; off <<= 1) {
    const int v = (t >= off) ? part[t - off] : 0;
    __syncthreads();
    part[t] += v;
    __syncthreads();
  }
  int run = part[t] - sum;
#pragma unroll
  for (int u = 0; u < JPT; ++u) {
    const int j = t * JPT + u;
    if (j < NPB) offs_t[k * NPB + j] = run;
    run += loc[u];
  }
  if (t == 255) total[k] = part[255];
}

// ---------------------------------------------------------------------------
// P2b: exclusive scan of the 782 bucket totals -> boffset[0..NB].
// ---------------------------------------------------------------------------
__global__ __launch_bounds__(1024) void part_scan2_kernel(
    const int* __restrict__ total, int* __restrict__ boffset,
    int* __restrict__ rowptr) {
  __shared__ int s[1024];
  const int tid = threadIdx.x;
  const int v = (tid < NB) ? total[tid] : 0;
  s[tid] = v;
  __syncthreads();
  for (int off = 1; off < 1024; off <<= 1) {
    const int t = (tid >= off) ? s[tid - off] : 0;
    __syncthreads();
    s[tid] += t;
    __syncthreads();
  }
  if (tid < NB) boffset[tid] = s[tid] - v;
  if (tid == 0) {
    boffset[NB] = N_EDGES;
    rowptr[N_NODES] = N_EDGES;
  }
}

// ---------------------------------------------------------------------------
// P3: deterministic fill. Each edge-block writes its edges to precomputed
// per-bucket bases; only LDS atomics for intra-block rank.
// Packed word: (src<<6)|(dst&63)  (src < 2^17, 23 bits total).
// ---------------------------------------------------------------------------
__global__ __launch_bounds__(256) void part_fill_kernel(
    const int* __restrict__ ei, const int* __restrict__ boffset,
    const int* __restrict__ offs_t, unsigned* __restrict__ pairs) {
  __shared__ int cur[NB];
  const int b = blockIdx.x;
  for (int k = threadIdx.x; k < NB; k += 256)
    cur[k] = boffset[k] + offs_t[k * NPB + b];
  __syncthreads();
  const int e0 = b * EPB;
  const int e1 = (e0 + EPB < N_EDGES) ? e0 + EPB : N_EDGES;
  for (int e = e0 + threadIdx.x; e < e1; e += 256) {
    const unsigned s = (unsigned)ei[e];
    const unsigned d = (unsigned)ei[N_EDGES + e];
    const int pos = atomicAdd(&cur[d >> 6], 1);
    pairs[pos] = (s << 6) | (d & 63u);
  }
}

// ---------------------------------------------------------------------------
// P4: per-bucket local CSR (64-node buckets, 782 blocks = ~3/CU).
// LDS hist of the 64 local nodes, 64-wide scan, scatter srcs into the
// bucket's contiguous global region. ~1024 edges per block.
// ---------------------------------------------------------------------------
__global__ __launch_bounds__(256) void bucket_csr_kernel(
    const unsigned* __restrict__ pairs, const int* __restrict__ boffset,
    int* __restrict__ rowptr, int* __restrict__ srcs) {
  __shared__ int cnt[64];
  __shared__ int sc[64];
  const int tid = threadIdx.x;
  const int base = boffset[blockIdx.x];
  const int limit = boffset[blockIdx.x + 1];

  if (tid < 64) cnt[tid] = 0;
  __syncthreads();
  for (int i = base + tid; i < limit; i += 256)
    atomicAdd(&cnt[pairs[i] & 63u], 1);
  __syncthreads();

  if (tid < 64) sc[tid] = cnt[tid];
  __syncthreads();
  for (int off = 1; off < 64; off <<= 1) {
    int v = 0;
    if (tid < 64 && tid >= off) v = sc[tid - off];
    __syncthreads();
    if (tid < 64) sc[tid] += v;
    __syncthreads();
  }

  if (tid < 64) {
    const int ex = base + sc[tid] - cnt[tid];  // exclusive global position
    const int node = blockIdx.x * 64 + tid;
    if (node < N_NODES) rowptr[node] = ex;
    cnt[tid] = ex;  // reuse as cursor
  }
  __syncthreads();

  for (int i = base + tid; i < limit; i += 256) {
    const unsigned p = pairs[i];
    const int pos = atomicAdd(&cnt[p & 63u], 1);
    srcs[pos] = (int)(p >> 6);
  }
}

// ---------------------------------------------------------------------------
// Fused preprocessing: blocks [0, CAST_BLOCKS) cast x f32->bf16 (8/thread);
// blocks [CAST_BLOCKS, +WFRAG_BLOCKS) shuffle W into MFMA fragment order:
// Wf[((kk*8+nt)*64 + lane)*8 + j] = W[nt*16+(lane&15)][kk*32+(lane>>4)*8+j]
// ---------------------------------------------------------------------------
__global__ __launch_bounds__(256) void prep_kernel(
    const float* __restrict__ x, const float* __restrict__ W,
    unsigned short* __restrict__ xb, unsigned short* __restrict__ Wf) {
  if (blockIdx.x < CAST_BLOCKS) {
    const int t = blockIdx.x * 256 + threadIdx.x;
    if (t >= (N_NODES * IN_CH) / 8) return;
    const float4 a = reinterpret_cast<const float4*>(x)[t * 2];
    const float4 c = reinterpret_cast<const float4*>(x)[t * 2 + 1];
    union { unsigned int u[4]; uint4 v; } o;
    o.u[0] = (unsigned)f2bf(a.x) | ((unsigned)f2bf(a.y) << 16);
    o.u[1] = (unsigned)f2bf(a.z) | ((unsigned)f2bf(a.w) << 16);
    o.u[2] = (unsigned)f2bf(c.x) | ((unsigned)f2bf(c.y) << 16);
    o.u[3] = (unsigned)f2bf(c.z) | ((unsigned)f2bf(c.w) << 16);
    reinterpret_cast<uint4*>(xb)[t] = o.v;
  } else {
    const int t = (blockIdx.x - CAST_BLOCKS) * 256 + threadIdx.x;
    if (t >= FEAT * OUT_CH) return;
    const int j = t & 7;
    const int l = (t >> 3) & 63;
    const int nt = (t >> 9) & 7;
    const int kk = t >> 12;
    const int o = nt * 16 + (l & 15);
    const int k = kk * 32 + (l >> 4) * 8 + j;
    Wf[t] = f2bf(W[o * FEAT + k]);
  }
}

// ---------------------------------------------------------------------------
// Gather hop (bf16): hout[n][c] = sum over in-edges(n) of hin[src][c].
// One wave per node; g=lane>>3 edge slot (8 in flight), s=lane&7 channel
// slice (uint4 = 16B). f32 register accumulate, shfl_xor combine. No atomics.
// ---------------------------------------------------------------------------
__global__ __launch_bounds__(256) void gather_kernel(
    const unsigned short* __restrict__ hin, const int* __restrict__ rowptr,
    const int* __restrict__ srcs, unsigned short* __restrict__ hout) {
  const int gid = blockIdx.x * blockDim.x + threadIdx.x;
  const int node = gid >> 6;
  if (node >= N_NODES) return;
  const int lane = threadIdx.x & 63;
  const int g = lane >> 3;
  const int s = lane & 7;

  const int beg = rowptr[node];
  const int end = rowptr[node + 1];

  float acc[8];
#pragma unroll
  for (int j = 0; j < 8; ++j) acc[j] = 0.0f;

  for (int i = beg + g; i < end; i += 8) {
    const int src = srcs[i];
    const uint4 v = *reinterpret_cast<const uint4*>(
        hin + (size_t)src * IN_CH + s * 8);
    acc[0] += bf2f(v.x & 0xffffu); acc[1] += bf2f(v.x >> 16);
    acc[2] += bf2f(v.y & 0xffffu); acc[3] += bf2f(v.y >> 16);
    acc[4] += bf2f(v.z & 0xffffu); acc[5] += bf2f(v.z >> 16);
    acc[6] += bf2f(v.w & 0xffffu); acc[7] += bf2f(v.w >> 16);
  }

#pragma unroll
  for (int j = 0; j < 8; ++j) {
    acc[j] += __shfl_xor(acc[j], 8);
    acc[j] += __shfl_xor(acc[j], 16);
    acc[j] += __shfl_xor(acc[j], 32);
  }

  if (g == 0) {
    union { unsigned u[4]; uint4 v; } o;
    o.u[0] = (unsigned)f2bf(acc[0]) | ((unsigned)f2bf(acc[1]) << 16);
    o.u[1] = (unsigned)f2bf(acc[2]) | ((unsigned)f2bf(acc[3]) << 16);
    o.u[2] = (unsigned)f2bf(acc[4]) | ((unsigned)f2bf(acc[5]) << 16);
    o.u[3] = (unsigned)f2bf(acc[6]) | ((unsigned)f2bf(acc[7]) << 16);
    *reinterpret_cast<uint4*>(hout + (size_t)node * IN_CH + s * 8) = o.v;
  }
}

// ---------------------------------------------------------------------------
// MFMA GEMM: out[n,o] = b[o] + [xb|h1b|h2b][n,:] @ W[o,:]  (bf16 in, f32 acc)
// One wave per 16-node tile; 8 n-tiles of 16 out-ch; K = 6 chunks of 32.
// C/D (m89-verified): D[(l>>4)*4+r][l&15].
// ---------------------------------------------------------------------------
__global__ __launch_bounds__(256) void gemm_kernel(
    const unsigned short* __restrict__ xb,
    const unsigned short* __restrict__ h1b,
    const unsigned short* __restrict__ h2b,
    const unsigned short* __restrict__ Wf, const float* __restrict__ b,
    float* __restrict__ out) {
  const int wave = (blockIdx.x * 256 + threadIdx.x) >> 6;
  if (wave >= N_TILES) return;
  const int lane = threadIdx.x & 63;
  const int node0 = wave * 16;
  const int mrow = lane & 15;
  const int kg = lane >> 4;

  f32x4 acc[8];
#pragma unroll
  for (int nt = 0; nt < 8; ++nt) acc[nt] = (f32x4){0.f, 0.f, 0.f, 0.f};

  const unsigned short* const srcarr[3] = {xb, h1b, h2b};
#pragma unroll
  for (int kk = 0; kk < 6; ++kk) {
    const unsigned short* a = srcarr[kk >> 1];
    const short8 af = *reinterpret_cast<const short8*>(
        a + (size_t)(node0 + mrow) * IN_CH + (kk & 1) * 32 + kg * 8);
#pragma unroll
    for (int nt = 0; nt < 8; ++nt) {
      const short8 bf = *reinterpret_cast<const short8*>(
          Wf + ((size_t)(kk * 8 + nt) * 64 + lane) * 8);
      acc[nt] = __builtin_amdgcn_mfma_f32_16x16x32_bf16(af, bf, acc[nt], 0, 0, 0);
    }
  }

#pragma unroll
  for (int nt = 0; nt < 8; ++nt) {
    const int oc = nt * 16 + mrow;
    const float bias = b[oc];
#pragma unroll
    for (int r = 0; r < 4; ++r) {
      out[(size_t)(node0 + kg * 4 + r) * OUT_CH + oc] = acc[nt][r] + bias;
    }
  }
}

extern "C" void kernel_launch(void* const* d_in, const int* in_sizes, int n_in,
                              void* d_out, int out_size, void* d_ws,
                              size_t ws_size, hipStream_t stream) {
  const float* x = (const float*)d_in[0];
  const int* ei = (const int*)d_in[1];   // [2, N_EDGES], int32 per harness
  const float* W = (const float*)d_in[2];
  const float* b = (const float*)d_in[3];
  float* out = (float*)d_out;

  // Workspace layout (no aliasing; ~33 MB of the ws).
  char* p = (char*)d_ws;
  auto take = [&](size_t bytes) {
    char* r = p;
    p += (bytes + 255) & ~(size_t)255;
    return r;
  };
  unsigned short* xb  = (unsigned short*)take((size_t)N_NODES * IN_CH * 2);
  unsigned short* h1b = (unsigned short*)take((size_t)N_NODES * IN_CH * 2);
  unsigned short* h2b = (unsigned short*)take((size_t)N_NODES * IN_CH * 2);
  unsigned short* Wf  = (unsigned short*)take((size_t)FEAT * OUT_CH * 2);
  int* total   = (int*)take((size_t)NB * 4);
  int* boffset = (int*)take((size_t)(NB + 1) * 4);
  int* rowptr  = (int*)take((size_t)(N_NODES + 1) * 4);
  unsigned* pairs = (unsigned*)take((size_t)N_EDGES * 4);
  int* srcs   = (int*)take((size_t)N_EDGES * 4);
  int* hist   = (int*)take((size_t)NPB * NB * 4);
  int* offs_t = (int*)take((size_t)NB * NPB * 4);

  // Deterministic two-level partition (no global atomics, no memset).
  part_hist_kernel<<<NPB, 256, 0, stream>>>(ei, hist);
  part_scan_kernel<<<NB, 256, 0, stream>>>(hist, offs_t, total);
  part_scan2_kernel<<<1, 1024, 0, stream>>>(total, boffset, rowptr);
  part_fill_kernel<<<NPB, 256, 0, stream>>>(ei, boffset, offs_t, pairs);
  bucket_csr_kernel<<<NB, 256, 0, stream>>>(pairs, boffset, rowptr, srcs);

  // Preprocessing (cast x, shuffle W) — one fused launch.
  prep_kernel<<<CAST_BLOCKS + WFRAG_BLOCKS, 256, 0, stream>>>(x, W, xb, Wf);

  // Hop 1: h1 = A*x; Hop 2: h2 = A*h1. Register gather, no atomics.
  const int gblocks = (N_NODES * 64 + 255) / 256;
  gather_kernel<<<gblocks, 256, 0, stream>>>(xb, rowptr, srcs, h1b);
  gather_kernel<<<gblocks, 256, 0, stream>>>(h1b, rowptr, srcs, h2b);

  // out = [xb|h1b|h2b] @ W.T + b via MFMA.
  const int gemmblocks = (N_TILES + 3) / 4;  // 4 waves per block
  gemm_kernel<<<gemmblocks, 256, 0, stream>>>(xb, h1b, h2b, Wf, b, out);
}

// Round 11
// 163.461 us; speedup vs baseline: 4.8782x; 1.0276x over previous
//
#include <hip/hip_runtime.h>

#define N_NODES 50000
#define N_EDGES 800000
#define IN_CH   64
#define OUT_CH  128
#define FEAT    192                          // IN_CH * 3 powers
#define NBK     ((N_NODES + 255) / 256)      // 196 dst-buckets of 256 nodes
#define EPB     4096                         // edges per partition block
#define NPB     ((N_EDGES + EPB - 1) / EPB)  // 196 edge-blocks
#define N_TILES (N_NODES / 16)               // 3125 wave-tiles for GEMM
#define CAST_BLOCKS  ((N_NODES * IN_CH / 8 + 255) / 256)  // 1563
#define WFRAG_BLOCKS ((FEAT * OUT_CH + 255) / 256)        // 96

typedef __attribute__((ext_vector_type(8))) short short8;  // 8 bf16 (4 VGPRs)
typedef __attribute__((ext_vector_type(4))) float f32x4;

static __device__ __forceinline__ unsigned short f2bf(float f) {
  unsigned int u = __float_as_uint(f);
  u += 0x7FFFu + ((u >> 16) & 1u);
  return (unsigned short)(u >> 16);
}
static __device__ __forceinline__ float bf2f(unsigned int s) {
  return __uint_as_float(s << 16);
}

// ---------------------------------------------------------------------------
// Fused launch 1:
//  blocks [0, NPB)           : per-edge-block LDS histogram of dst>>8,
//                              written TRANSPOSED: hist_t[k*NPB + b]
//  blocks [NPB, +CAST_BLOCKS): cast x f32 -> bf16 (8 elems/thread)
//  blocks [.., +WFRAG_BLOCKS): W -> Wf bf16 in MFMA fragment order
// ---------------------------------------------------------------------------
__global__ __launch_bounds__(256) void hist_prep_kernel(
    const int* __restrict__ ei, const float* __restrict__ x,
    const float* __restrict__ W, int* __restrict__ hist_t,
    unsigned short* __restrict__ xb, unsigned short* __restrict__ Wf) {
  if (blockIdx.x < NPB) {
    __shared__ int lh[NBK];
    const int b = blockIdx.x;
    for (int i = threadIdx.x; i < NBK; i += 256) lh[i] = 0;
    __syncthreads();
    const int e0 = b * EPB;
    const int e1 = (e0 + EPB < N_EDGES) ? e0 + EPB : N_EDGES;
    for (int e = e0 + threadIdx.x; e < e1; e += 256)
      atomicAdd(&lh[((unsigned)ei[N_EDGES + e]) >> 8], 1);
    __syncthreads();
    for (int k = threadIdx.x; k < NBK; k += 256) hist_t[k * NPB + b] = lh[k];
  } else if (blockIdx.x < NPB + CAST_BLOCKS) {
    const int t = (blockIdx.x - NPB) * 256 + threadIdx.x;
    if (t >= (N_NODES * IN_CH) / 8) return;
    const float4 a = reinterpret_cast<const float4*>(x)[t * 2];
    const float4 c = reinterpret_cast<const float4*>(x)[t * 2 + 1];
    union { unsigned int u[4]; uint4 v; } o;
    o.u[0] = (unsigned)f2bf(a.x) | ((unsigned)f2bf(a.y) << 16);
    o.u[1] = (unsigned)f2bf(a.z) | ((unsigned)f2bf(a.w) << 16);
    o.u[2] = (unsigned)f2bf(c.x) | ((unsigned)f2bf(c.y) << 16);
    o.u[3] = (unsigned)f2bf(c.z) | ((unsigned)f2bf(c.w) << 16);
    reinterpret_cast<uint4*>(xb)[t] = o.v;
  } else {
    const int t = (blockIdx.x - NPB - CAST_BLOCKS) * 256 + threadIdx.x;
    if (t >= FEAT * OUT_CH) return;
    const int j = t & 7;
    const int l = (t >> 3) & 63;
    const int nt = (t >> 9) & 7;
    const int kk = t >> 12;
    const int o = nt * 16 + (l & 15);
    const int k = kk * 32 + (l >> 4) * 8 + j;
    Wf[t] = f2bf(W[o * FEAT + k]);
  }
}

// ---------------------------------------------------------------------------
// P2: per-bucket exclusive scan across the 196 edge-blocks (contiguous row
// read of hist_t). Block k: offs_t[k][j] = sum_{j'<j}; total[k] = full sum.
// ---------------------------------------------------------------------------
__global__ __launch_bounds__(256) void part_scan_kernel(
    const int* __restrict__ hist_t, int* __restrict__ offs_t,
    int* __restrict__ total) {
  __shared__ int s[256];
  const int k = blockIdx.x;
  const int t = threadIdx.x;
  const int v = (t < NPB) ? hist_t[k * NPB + t] : 0;
  s[t] = v;
  __syncthreads();
  for (int off = 1; off < 256; off <<= 1) {
    const int u = (t >= off) ? s[t - off] : 0;
    __syncthreads();
    s[t] += u;
    __syncthreads();
  }
  if (t < NPB) offs_t[k * NPB + t] = s[t] - v;  // exclusive
  if (t == 255) total[k] = s[255];
}

// ---------------------------------------------------------------------------
// P3: deterministic fill. Each edge-block derives the 196 bucket bases from
// `total` via an LDS scan (no global boffset), adds its own offs_t column,
// then writes packed (src<<8)|(dst&255) at per-bucket LDS cursors.
// ---------------------------------------------------------------------------
__global__ __launch_bounds__(256) void part_fill_kernel(
    const int* __restrict__ ei, const int* __restrict__ total,
    const int* __restrict__ offs_t, unsigned* __restrict__ pairs) {
  __shared__ int s[256];
  __shared__ int cur[NBK];
  const int b = blockIdx.x;
  const int t = threadIdx.x;
  const int v = (t < NBK) ? total[t] : 0;
  s[t] = v;
  __syncthreads();
  for (int off = 1; off < 256; off <<= 1) {
    const int u = (t >= off) ? s[t - off] : 0;
    __syncthreads();
    s[t] += u;
    __syncthreads();
  }
  if (t < NBK) cur[t] = (s[t] - v) + offs_t[t * NPB + b];
  __syncthreads();

  const int e0 = b * EPB;
  const int e1 = (e0 + EPB < N_EDGES) ? e0 + EPB : N_EDGES;
  for (int e = e0 + t; e < e1; e += 256) {
    const unsigned sv = (unsigned)ei[e];
    const unsigned d = (unsigned)ei[N_EDGES + e];
    const int pos = atomicAdd(&cur[d >> 8], 1);
    pairs[pos] = (sv << 8) | (d & 255u);
  }
}

// ---------------------------------------------------------------------------
// P4: per-bucket local CSR (256-node buckets). Re-derive bucket base from
// `total` (LDS scan), LDS hist of the 256 local nodes, LDS scan, scatter
// srcs into the bucket's contiguous region; emit rowptr.
// ---------------------------------------------------------------------------
__global__ __launch_bounds__(256) void bucket_csr_kernel(
    const unsigned* __restrict__ pairs, const int* __restrict__ total,
    int* __restrict__ rowptr, int* __restrict__ srcs) {
  __shared__ int s[256];
  __shared__ int bofs[NBK];
  __shared__ int cnt[256];
  __shared__ int sc[256];
  const int tid = threadIdx.x;
  {
    const int v = (tid < NBK) ? total[tid] : 0;
    s[tid] = v;
    __syncthreads();
    for (int off = 1; off < 256; off <<= 1) {
      const int u = (tid >= off) ? s[tid - off] : 0;
      __syncthreads();
      s[tid] += u;
      __syncthreads();
    }
    if (tid < NBK) bofs[tid] = s[tid] - v;
  }
  __syncthreads();

  const int k = blockIdx.x;
  const int base = bofs[k];
  const int limit = base + total[k];

  cnt[tid] = 0;
  __syncthreads();
  for (int i = base + tid; i < limit; i += 256)
    atomicAdd(&cnt[pairs[i] & 255u], 1);
  __syncthreads();

  const int v = cnt[tid];
  sc[tid] = v;
  __syncthreads();
  for (int off = 1; off < 256; off <<= 1) {
    const int u = (tid >= off) ? sc[tid - off] : 0;
    __syncthreads();
    sc[tid] += u;
    __syncthreads();
  }
  const int ex = base + sc[tid] - v;  // exclusive global position

  const int node = k * 256 + tid;
  if (node < N_NODES) rowptr[node] = ex;
  if (k == 0 && tid == 0) rowptr[N_NODES] = N_EDGES;

  cnt[tid] = ex;  // reuse as cursor
  __syncthreads();
  for (int i = base + tid; i < limit; i += 256) {
    const unsigned p = pairs[i];
    const int pos = atomicAdd(&cnt[p & 255u], 1);
    srcs[pos] = (int)(p >> 8);
  }
}

// ---------------------------------------------------------------------------
// Gather hop (bf16): hout[n][c] = sum over in-edges(n) of hin[src][c].
// One wave per node; g=lane>>3 edge slot (8 in flight), s=lane&7 channel
// slice (uint4 = 16B). f32 register accumulate, shfl_xor combine. No atomics.
// ---------------------------------------------------------------------------
__global__ __launch_bounds__(256) void gather_kernel(
    const unsigned short* __restrict__ hin, const int* __restrict__ rowptr,
    const int* __restrict__ srcs, unsigned short* __restrict__ hout) {
  const int gid = blockIdx.x * blockDim.x + threadIdx.x;
  const int node = gid >> 6;
  if (node >= N_NODES) return;
  const int lane = threadIdx.x & 63;
  const int g = lane >> 3;
  const int s = lane & 7;

  const int beg = rowptr[node];
  const int end = rowptr[node + 1];

  float acc[8];
#pragma unroll
  for (int j = 0; j < 8; ++j) acc[j] = 0.0f;

  for (int i = beg + g; i < end; i += 8) {
    const int src = srcs[i];
    const uint4 v = *reinterpret_cast<const uint4*>(
        hin + (size_t)src * IN_CH + s * 8);
    acc[0] += bf2f(v.x & 0xffffu); acc[1] += bf2f(v.x >> 16);
    acc[2] += bf2f(v.y & 0xffffu); acc[3] += bf2f(v.y >> 16);
    acc[4] += bf2f(v.z & 0xffffu); acc[5] += bf2f(v.z >> 16);
    acc[6] += bf2f(v.w & 0xffffu); acc[7] += bf2f(v.w >> 16);
  }

#pragma unroll
  for (int j = 0; j < 8; ++j) {
    acc[j] += __shfl_xor(acc[j], 8);
    acc[j] += __shfl_xor(acc[j], 16);
    acc[j] += __shfl_xor(acc[j], 32);
  }

  if (g == 0) {
    union { unsigned u[4]; uint4 v; } o;
    o.u[0] = (unsigned)f2bf(acc[0]) | ((unsigned)f2bf(acc[1]) << 16);
    o.u[1] = (unsigned)f2bf(acc[2]) | ((unsigned)f2bf(acc[3]) << 16);
    o.u[2] = (unsigned)f2bf(acc[4]) | ((unsigned)f2bf(acc[5]) << 16);
    o.u[3] = (unsigned)f2bf(acc[6]) | ((unsigned)f2bf(acc[7]) << 16);
    *reinterpret_cast<uint4*>(hout + (size_t)node * IN_CH + s * 8) = o.v;
  }
}

// ---------------------------------------------------------------------------
// MFMA GEMM: out[n,o] = b[o] + [xb|h1b|h2b][n,:] @ W[o,:]  (bf16 in, f32 acc)
// One wave per 16-node tile; 8 n-tiles of 16 out-ch; K = 6 chunks of 32.
// C/D (m89-verified): D[(l>>4)*4+r][l&15].
// ---------------------------------------------------------------------------
__global__ __launch_bounds__(256) void gemm_kernel(
    const unsigned short* __restrict__ xb,
    const unsigned short* __restrict__ h1b,
    const unsigned short* __restrict__ h2b,
    const unsigned short* __restrict__ Wf, const float* __restrict__ b,
    float* __restrict__ out) {
  const int wave = (blockIdx.x * 256 + threadIdx.x) >> 6;
  if (wave >= N_TILES) return;
  const int lane = threadIdx.x & 63;
  const int node0 = wave * 16;
  const int mrow = lane & 15;
  const int kg = lane >> 4;

  f32x4 acc[8];
#pragma unroll
  for (int nt = 0; nt < 8; ++nt) acc[nt] = (f32x4){0.f, 0.f, 0.f, 0.f};

  const unsigned short* const srcarr[3] = {xb, h1b, h2b};
#pragma unroll
  for (int kk = 0; kk < 6; ++kk) {
    const unsigned short* a = srcarr[kk >> 1];
    const short8 af = *reinterpret_cast<const short8*>(
        a + (size_t)(node0 + mrow) * IN_CH + (kk & 1) * 32 + kg * 8);
#pragma unroll
    for (int nt = 0; nt < 8; ++nt) {
      const short8 bf = *reinterpret_cast<const short8*>(
          Wf + ((size_t)(kk * 8 + nt) * 64 + lane) * 8);
      acc[nt] = __builtin_amdgcn_mfma_f32_16x16x32_bf16(af, bf, acc[nt], 0, 0, 0);
    }
  }

#pragma unroll
  for (int nt = 0; nt < 8; ++nt) {
    const int oc = nt * 16 + mrow;
    const float bias = b[oc];
#pragma unroll
    for (int r = 0; r < 4; ++r) {
      out[(size_t)(node0 + kg * 4 + r) * OUT_CH + oc] = acc[nt][r] + bias;
    }
  }
}

extern "C" void kernel_launch(void* const* d_in, const int* in_sizes, int n_in,
                              void* d_out, int out_size, void* d_ws,
                              size_t ws_size, hipStream_t stream) {
  const float* x = (const float*)d_in[0];
  const int* ei = (const int*)d_in[1];   // [2, N_EDGES], int32 per harness
  const float* W = (const float*)d_in[2];
  const float* b = (const float*)d_in[3];
  float* out = (float*)d_out;

  // Workspace layout (no aliasing; ~26 MB of the ws).
  char* p = (char*)d_ws;
  auto take = [&](size_t bytes) {
    char* r = p;
    p += (bytes + 255) & ~(size_t)255;
    return r;
  };
  unsigned short* xb  = (unsigned short*)take((size_t)N_NODES * IN_CH * 2);
  unsigned short* h1b = (unsigned short*)take((size_t)N_NODES * IN_CH * 2);
  unsigned short* h2b = (unsigned short*)take((size_t)N_NODES * IN_CH * 2);
  unsigned short* Wf  = (unsigned short*)take((size_t)FEAT * OUT_CH * 2);
  int* total  = (int*)take((size_t)NBK * 4);
  int* rowptr = (int*)take((size_t)(N_NODES + 1) * 4);
  unsigned* pairs = (unsigned*)take((size_t)N_EDGES * 4);
  int* srcs   = (int*)take((size_t)N_EDGES * 4);
  int* hist_t = (int*)take((size_t)NBK * NPB * 4);
  int* offs_t = (int*)take((size_t)NBK * NPB * 4);

  // 1) fused: edge-block histogram (transposed) + x cast + W fragment shuffle
  hist_prep_kernel<<<NPB + CAST_BLOCKS + WFRAG_BLOCKS, 256, 0, stream>>>(
      ei, x, W, hist_t, xb, Wf);
  // 2) per-bucket scan across edge-blocks
  part_scan_kernel<<<NBK, 256, 0, stream>>>(hist_t, offs_t, total);
  // 3) deterministic bucket fill (boffset derived in LDS)
  part_fill_kernel<<<NPB, 256, 0, stream>>>(ei, total, offs_t, pairs);
  // 4) per-bucket local CSR -> rowptr, srcs
  bucket_csr_kernel<<<NBK, 256, 0, stream>>>(pairs, total, rowptr, srcs);

  // 5/6) Hop 1: h1 = A*x; Hop 2: h2 = A*h1. Register gather, no atomics.
  const int gblocks = (N_NODES * 64 + 255) / 256;
  gather_kernel<<<gblocks, 256, 0, stream>>>(xb, rowptr, srcs, h1b);
  gather_kernel<<<gblocks, 256, 0, stream>>>(h1b, rowptr, srcs, h2b);

  // 7) out = [xb|h1b|h2b] @ W.T + b via MFMA.
  const int gemmblocks = (N_TILES + 3) / 4;  // 4 waves per block
  gemm_kernel<<<gemmblocks, 256, 0, stream>>>(xb, h1b, h2b, Wf, b, out);
}